// Round 4
// baseline (351.954 us; speedup 1.0000x reference)
//
#include <hip/hip_runtime.h>

#define NB     64
#define CCH    256
#define HW     20480       // 128*160
#define PXB    1024        // px per block
#define NPR    (HW/PXB)    // 20 pixel ranges
#define GRID_MS (2*4*16*NPR)   // 2560 blocks

// Workspace layout (bytes):
//   sums [2 replicas][2 tensors][64][256] f32 = 262144, zeroed
//   counts [65] i32 @ 262144 ; acc @ 262404 ; ticket @ 262408 ; memset [0,262412)
//   pS aliases replica1/tensor0 = ws+131072 ; pT = ws+196608 (R5-verified safe)
#define REP_STRIDE (2 * NB * CCH)
#define WS_COUNTS 262144
#define WS_ACC    262404
#define WS_TICKET 262408
#define WS_ZERO   262412
#define WS_PS     131072
#define WS_PT     196608

#define ABIN 17    // padded LDS row stride (floats) for bin accumulator

// ---------------------------------------------------------------------------
// Main: segment-sum via LDS f32 atomics (R9).
// R0/R6/R7/R8 all tied at ~65us across four totally different staging
// structures -> the invariant was the one-hot+MFMA formulation itself
// (~900 VALU/thread building A-fragments + 32 chained MFMAs). Replace with
// the native scatter-add: ds_add_f32 (non-returning, fire-and-forget) into
// accL[bin][chLocal]. Wave layout keeps 16 distinct channels per instr
// (<=4-way conflicts; 2-way is free per m136). Bin 64 (invalid) lands in a
// padded row that is never read (matches reference [:NUM_BINS] drop).
// f32 accumulation (no bf16 rounding) -- strictly more accurate than R8.
__global__ __launch_bounds__(256, 6)
void k_msum(const float* __restrict__ predsS,
            const float* __restrict__ predsT,
            const float* __restrict__ depth,
            float* __restrict__ sums,
            int* __restrict__ counts) {
    int tid = threadIdx.x;
    int blk = blockIdx.x;
    int prange = blk % NPR;
    int group  = blk / NPR;          // 0..127 = [tensor:1][n:2][cg:4]
    int tensor = group >> 6;
    int n  = (group >> 4) & 3;
    int cg = group & 15;
    int px0 = prange * PXB;

    const float* xbase = (tensor ? predsT : predsS)
                       + (size_t)(n * CCH + cg * 16) * HW + px0;
    const float* dbase = depth + n * HW + px0;

    __shared__ float accL[(NB + 1) * ABIN];  // 4420 B; row 64 = invalid-bin sink
    __shared__ unsigned char sBin[PXB];      // 1 KB
    __shared__ int lhist[NB + 1];

    int lane = tid & 63, wv = tid >> 6;
    int l15 = lane & 15, q = lane >> 4;

    // Depth loads first (oldest in vmcnt queue -> binning waits only on these).
    float dv[4];
    #pragma unroll
    for (int r = 0; r < 4; ++r) dv[r] = dbase[tid + r * 256];

    // This lane's element stream: channel l15, px base wv*256 + q*8.
    // Chunk ks lives at fb + ks*32 (two float4s: +0, +4).
    const float* fb = xbase + (size_t)l15 * HW + wv * 256 + q * 8;
    float4 va[4], vb[4];                     // 4-deep prefetch
    #pragma unroll
    for (int p = 0; p < 4; ++p) {
        va[p] = *(const float4*)(fb + p * 32);
        vb[p] = *(const float4*)(fb + p * 32 + 4);
    }

    // Zero accumulator (65*17 = 1105 floats) while loads fly.
    for (int i = tid; i < (NB + 1) * ABIN; i += 256) accL[i] = 0.0f;

    bool desig = (tensor == 0) && (cg == 0); // 80 blocks cover depth exactly once
    if (desig && tid < NB + 1) lhist[tid] = 0;

    #pragma unroll
    for (int r = 0; r < 4; ++r) {            // binning (waits only on dv loads)
        float f = dv[r] * 64.0f;
        int b;
        if (!(f >= 0.0f) || f > 64.0f) b = NB;   // NaN via !(f>=0)
        else b = (int)f;                          // f==64.0 -> 64 (matches ref)
        sBin[tid + r * 256] = (unsigned char)b;
    }

    __syncthreads();   // accL zeroed + sBin ready (barrier 1 of 2)

    #pragma unroll
    for (int ks = 0; ks < 8; ++ks) {
        int pi = ks & 3;
        unsigned long long bv = *(const unsigned long long*)&sBin[wv * 256 + ks * 32 + q * 8];
        float4 A = va[pi], B = vb[pi];
        if (ks < 4) {   // prefetch ks+4 (regs freed by the copy above)
            va[pi] = *(const float4*)(fb + (ks + 4) * 32);
            vb[pi] = *(const float4*)(fb + (ks + 4) * 32 + 4);
        }
        float vals[8] = {A.x, A.y, A.z, A.w, B.x, B.y, B.z, B.w};
        #pragma unroll
        for (int j = 0; j < 8; ++j) {
            int b = (int)((bv >> (8 * j)) & 0xFFull);
            atomicAdd(&accL[b * ABIN + l15], vals[j]);   // ds_add_f32, no return
        }
    }

    __syncthreads();   // all ds_add drained (barrier 2 of 2)

    if (desig) {   // histogram overlaps the epilogue's global atomics
        for (int i = tid; i < PXB; i += 256) atomicAdd(&lhist[sBin[i]], 1);
    }
    float* dst = sums + (size_t)(blk & 1) * REP_STRIDE
               + (size_t)tensor * NB * CCH + cg * 16;
    #pragma unroll
    for (int k = 0; k < 4; ++k) {
        int e = tid + k * 256;               // e = bin*16 + chLocal
        float s = accL[(e >> 4) * ABIN + (e & 15)];
        atomicAdd(&dst[(e >> 4) * CCH + (e & 15)], s);
    }
    if (desig && tid < NB + 1 && lhist[tid] != 0) atomicAdd(&counts[tid], lhist[tid]);
}

// ---------------------------------------------------------------------------
// Protos: 64 blocks x 256 threads. Folds 2 sums replicas, normalizes.
// (R7 version restored verbatim -- the R8 fusion was a -53us regression.)
__global__ __launch_bounds__(256) void k_protos(const float* __restrict__ sums,
                                                const int* __restrict__ counts,
                                                float* __restrict__ pS,
                                                float* __restrict__ pT) {
    int b = blockIdx.x, t = threadIdx.x;
    int ci = counts[b];
    float cnt = (float)(ci < 1 ? 1 : ci);
    float mS = (sums[b * CCH + t] + sums[REP_STRIDE + b * CCH + t]) / cnt;
    float mT = (sums[(NB + b) * CCH + t] + sums[REP_STRIDE + (NB + b) * CCH + t]) / cnt;
    float ss = mS * mS, st = mT * mT;
    #pragma unroll
    for (int o = 32; o; o >>= 1) {
        ss += __shfl_xor(ss, o, 64);
        st += __shfl_xor(st, o, 64);
    }
    __shared__ float rs[4], rt[4];
    int w = t >> 6;
    if ((t & 63) == 0) { rs[w] = ss; rt[w] = st; }
    __syncthreads();
    float nS = sqrtf(rs[0] + rs[1] + rs[2] + rs[3]);
    float nT = sqrtf(rt[0] + rt[1] + rt[2] + rt[3]);
    pS[b * CCH + t] = mS / fmaxf(nS, 1e-12f);
    pT[b * CCH + t] = mT / fmaxf(nT, 1e-12f);
}

// ---------------------------------------------------------------------------
// Sims + loss: 64 blocks (row i) x 256 threads. Ticketed final write.
__global__ __launch_bounds__(256) void k_sim(const float* __restrict__ pS,
                                             const float* __restrict__ pT,
                                             float* __restrict__ acc,
                                             unsigned int* __restrict__ ticket,
                                             float* __restrict__ out) {
    int i = blockIdx.x;
    int t = threadIdx.x;
    int j = t & 63, seg = t >> 6;
    __shared__ float rowS[CCH], rowT[CCH];
    rowS[t] = pS[i * CCH + t];
    rowT[t] = pT[i * CCH + t];
    __syncthreads();
    const float4* Sj = (const float4*)(pS + j * CCH + seg * 64);
    const float4* Tj = (const float4*)(pT + j * CCH + seg * 64);
    const float4* Si = (const float4*)(rowS + seg * 64);
    const float4* Ti = (const float4*)(rowT + seg * 64);
    float dS = 0.0f, dT = 0.0f;
    #pragma unroll
    for (int k = 0; k < 16; ++k) {
        float4 a = Si[k], b = Sj[k];
        dS += a.x * b.x + a.y * b.y + a.z * b.z + a.w * b.w;
        float4 c = Ti[k], d = Tj[k];
        dT += c.x * d.x + c.y * d.y + c.z * d.z + c.w * d.w;
    }
    __shared__ float sS[4][64], sT[4][64];
    sS[seg][j] = dS;
    sT[seg][j] = dT;
    __syncthreads();
    if (t < 64) {
        float fS = sS[0][t] + sS[1][t] + sS[2][t] + sS[3][t];
        float fT = sT[0][t] + sT[1][t] + sT[2][t] + sT[3][t];
        float e = fS - fT;
        e = e * e;
        #pragma unroll
        for (int o = 32; o; o >>= 1) e += __shfl_xor(e, o, 64);
        if (t == 0) {
            atomicAdd(acc, e);
            __threadfence();
            unsigned int r = atomicAdd(ticket, 1u);
            if (r == NB - 1) {
                float tot = atomicAdd(acc, 0.0f);   // device-scope read
                out[0] = tot * (1.0f / (float)(NB * NB));
            }
        }
    }
}

extern "C" void kernel_launch(void* const* d_in, const int* in_sizes, int n_in,
                              void* d_out, int out_size, void* d_ws, size_t ws_size,
                              hipStream_t stream) {
    const float* predsS = (const float*)d_in[0];
    const float* predsT = (const float*)d_in[1];
    const float* depth  = (const float*)d_in[2];
    char* ws = (char*)d_ws;
    float* sums = (float*)ws;
    int* counts = (int*)(ws + WS_COUNTS);
    float* acc = (float*)(ws + WS_ACC);
    unsigned int* ticket = (unsigned int*)(ws + WS_TICKET);
    float* pS = (float*)(ws + WS_PS);
    float* pT = (float*)(ws + WS_PT);

    hipMemsetAsync(ws, 0, WS_ZERO, stream);
    k_msum<<<GRID_MS, 256, 0, stream>>>(predsS, predsT, depth, sums, counts);
    k_protos<<<NB, 256, 0, stream>>>(sums, counts, pS, pT);
    k_sim<<<NB, 256, 0, stream>>>(pS, pT, acc, ticket, (float*)d_out);
}

// Round 6
// 194.091 us; speedup vs baseline: 1.8133x; 1.8133x over previous
//
#include <hip/hip_runtime.h>

#define NB     64
#define CCH    256
#define HW     20480       // 128*160
#define PXB    1024        // px per block
#define NPR    (HW/PXB)    // 20 pixel ranges
#define GRID_MS (2*4*16*NPR)   // 2560 blocks

// Workspace layout (bytes):
//   sums [2 replicas][2 tensors][64][256] f32 = 262144, zeroed
//   counts [65] i32 @ 262144 ; acc @ 262404 ; ticket @ 262408 ; memset [0,262412)
//   pS aliases replica1/tensor0 = ws+131072 ; pT = ws+196608 (R5-verified safe)
#define REP_STRIDE (2 * NB * CCH)
#define WS_COUNTS 262144
#define WS_ACC    262404
#define WS_TICKET 262408
#define WS_ZERO   262412
#define WS_PS     131072
#define WS_PT     196608

typedef __attribute__((ext_vector_type(8))) short short8;
typedef __attribute__((ext_vector_type(4))) float f32x4;

// ---------------------------------------------------------------------------
// Main: segment-sum as one-hot MFMA, register-direct (R8 structure, best at
// 65.3us). R10/R11: feature loads are NON-TEMPORAL (single-use by
// construction; 2.6M L2-miss lines thrash the 32KB L1 for nothing). Theory:
// k_msum is pinned at 168MB / 2.6TB/s = 65us across four structures AND
// across L3/HBM residency -> per-CU miss-path service bound; nt bypasses L1
// allocation on the single-use stream. Depth loads stay cached (32 blocks
// share each depth line). R11 fixes R10's compile error: the builtin needs
// a clang ext_vector type, not HIP_vector_type<float,4>.
// Layouts (R3-R5 verified): A: m=lane&15,k=q*8+j; B: n=lane&15,k=q*8+j;
// D: col=lane&15,row=q*4+reg.
__global__ __launch_bounds__(256, 6)
void k_msum(const float* __restrict__ predsS,
            const float* __restrict__ predsT,
            const float* __restrict__ depth,
            float* __restrict__ sums,
            int* __restrict__ counts) {
    int tid = threadIdx.x;
    int blk = blockIdx.x;
    int prange = blk % NPR;
    int group  = blk / NPR;          // 0..127 = [tensor:1][n:2][cg:4]
    int tensor = group >> 6;
    int n  = (group >> 4) & 3;
    int cg = group & 15;
    int px0 = prange * PXB;

    const float* xbase = (tensor ? predsT : predsS)
                       + (size_t)(n * CCH + cg * 16) * HW + px0;
    const float* dbase = depth + n * HW + px0;

    __shared__ unsigned char sBin[PXB];      // 1 KB
    __shared__ int lhist[NB + 1];
    __shared__ float red[4096];              // 16 KB cross-wave reduce

    int lane = tid & 63, wv = tid >> 6;
    int l15 = lane & 15, q = lane >> 4;

    // Depth loads first (oldest in vmcnt queue -> binning waits only on these).
    float dv[4];
    #pragma unroll
    for (int r = 0; r < 4; ++r) dv[r] = dbase[tid + r * 256];

    // This lane's fragment stream: channel l15, px base wv*256 + q*8.
    // Fragment ks lives at fb + ks*32 (two 16B loads: +0, +4).
    const float* fb = xbase + (size_t)l15 * HW + wv * 256 + q * 8;
    f32x4 va[4], vb[4];                      // 4-deep prefetch
    #pragma unroll
    for (int p = 0; p < 4; ++p) {
        va[p] = __builtin_nontemporal_load((const f32x4*)(fb + p * 32));
        vb[p] = __builtin_nontemporal_load((const f32x4*)(fb + p * 32 + 4));
    }

    bool desig = (tensor == 0) && (cg == 0); // 80 blocks cover depth exactly once
    if (desig && tid < NB + 1) lhist[tid] = 0;

    #pragma unroll
    for (int r = 0; r < 4; ++r) {            // binning (waits only on dv loads)
        float f = dv[r] * 64.0f;
        int b;
        if (!(f >= 0.0f) || f > 64.0f) b = NB;   // NaN via !(f>=0)
        else b = (int)f;                          // f==64.0 -> 64 (matches ref)
        sBin[tid + r * 256] = (unsigned char)b;
    }

    f32x4 acc[4];
    #pragma unroll
    for (int mt = 0; mt < 4; ++mt) acc[mt] = (f32x4)0.0f;

    __syncthreads();   // sBin ready (barrier 1 of 2)

    #pragma unroll
    for (int ks = 0; ks < 8; ++ks) {
        int pi = ks & 3;
        unsigned long long bv = *(const unsigned long long*)&sBin[wv * 256 + ks * 32 + q * 8];
        // convert current fragment to bf16 (round-half-up, R5-validated)
        f32x4 A = va[pi], B = vb[pi];
        unsigned u0 = __float_as_uint(A.x), u1 = __float_as_uint(A.y);
        unsigned u2 = __float_as_uint(A.z), u3 = __float_as_uint(A.w);
        unsigned u4 = __float_as_uint(B.x), u5 = __float_as_uint(B.y);
        unsigned u6 = __float_as_uint(B.z), u7 = __float_as_uint(B.w);
        union { short8 s; unsigned u[4]; } bh;
        bh.u[0] = ((u0 + 0x8000u) >> 16) | ((u1 + 0x8000u) & 0xFFFF0000u);
        bh.u[1] = ((u2 + 0x8000u) >> 16) | ((u3 + 0x8000u) & 0xFFFF0000u);
        bh.u[2] = ((u4 + 0x8000u) >> 16) | ((u5 + 0x8000u) & 0xFFFF0000u);
        bh.u[3] = ((u6 + 0x8000u) >> 16) | ((u7 + 0x8000u) & 0xFFFF0000u);
        if (ks < 4) {   // prefetch ks+4 (regs freed by the copy above)
            va[pi] = __builtin_nontemporal_load((const f32x4*)(fb + (ks + 4) * 32));
            vb[pi] = __builtin_nontemporal_load((const f32x4*)(fb + (ks + 4) * 32 + 4));
        }
        #pragma unroll
        for (int mt = 0; mt < 4; ++mt) {
            int tgt = mt * 16 + l15;
            short8 afr;
            #pragma unroll
            for (int j = 0; j < 8; ++j)
                afr[j] = ((int)((bv >> (8 * j)) & 0xFFull) == tgt) ? (short)0x3F80 : (short)0;
            acc[mt] = __builtin_amdgcn_mfma_f32_16x16x32_bf16(afr, bh.s, acc[mt], 0, 0, 0);
        }
    }

    // cross-wave reduce (red unused until here -> no barrier needed pre-write)
    #pragma unroll
    for (int mt = 0; mt < 4; ++mt)
        #pragma unroll
        for (int r = 0; r < 4; ++r)
            red[wv * 1024 + (mt * 16 + q * 4 + r) * 16 + l15] = acc[mt][r];
    if (desig) {   // histogram overlaps reduce writes
        for (int i = tid; i < PXB; i += 256) atomicAdd(&lhist[sBin[i]], 1);
    }
    __syncthreads();   // barrier 2 of 2
    float* dst = sums + (size_t)(blk & 1) * REP_STRIDE
               + (size_t)tensor * NB * CCH + cg * 16;
    #pragma unroll
    for (int k = 0; k < 4; ++k) {
        int e = tid + k * 256;               // e = bin*16 + chLocal
        float s = red[e] + red[1024 + e] + red[2048 + e] + red[3072 + e];
        atomicAdd(&dst[(e >> 4) * CCH + (e & 15)], s);
    }
    if (desig && tid < NB + 1 && lhist[tid] != 0) atomicAdd(&counts[tid], lhist[tid]);
}

// ---------------------------------------------------------------------------
// Protos: 64 blocks x 256 threads. Folds 2 sums replicas, normalizes.
// (Original fast pair restored -- R8's fusion was a -53us regression.)
__global__ __launch_bounds__(256) void k_protos(const float* __restrict__ sums,
                                                const int* __restrict__ counts,
                                                float* __restrict__ pS,
                                                float* __restrict__ pT) {
    int b = blockIdx.x, t = threadIdx.x;
    int ci = counts[b];
    float cnt = (float)(ci < 1 ? 1 : ci);
    float mS = (sums[b * CCH + t] + sums[REP_STRIDE + b * CCH + t]) / cnt;
    float mT = (sums[(NB + b) * CCH + t] + sums[REP_STRIDE + (NB + b) * CCH + t]) / cnt;
    float ss = mS * mS, st = mT * mT;
    #pragma unroll
    for (int o = 32; o; o >>= 1) {
        ss += __shfl_xor(ss, o, 64);
        st += __shfl_xor(st, o, 64);
    }
    __shared__ float rs[4], rt[4];
    int w = t >> 6;
    if ((t & 63) == 0) { rs[w] = ss; rt[w] = st; }
    __syncthreads();
    float nS = sqrtf(rs[0] + rs[1] + rs[2] + rs[3]);
    float nT = sqrtf(rt[0] + rt[1] + rt[2] + rt[3]);
    pS[b * CCH + t] = mS / fmaxf(nS, 1e-12f);
    pT[b * CCH + t] = mT / fmaxf(nT, 1e-12f);
}

// ---------------------------------------------------------------------------
// Sims + loss: 64 blocks (row i) x 256 threads. Ticketed final write.
__global__ __launch_bounds__(256) void k_sim(const float* __restrict__ pS,
                                             const float* __restrict__ pT,
                                             float* __restrict__ acc,
                                             unsigned int* __restrict__ ticket,
                                             float* __restrict__ out) {
    int i = blockIdx.x;
    int t = threadIdx.x;
    int j = t & 63, seg = t >> 6;
    __shared__ float rowS[CCH], rowT[CCH];
    rowS[t] = pS[i * CCH + t];
    rowT[t] = pT[i * CCH + t];
    __syncthreads();
    const float4* Sj = (const float4*)(pS + j * CCH + seg * 64);
    const float4* Tj = (const float4*)(pT + j * CCH + seg * 64);
    const float4* Si = (const float4*)(rowS + seg * 64);
    const float4* Ti = (const float4*)(rowT + seg * 64);
    float dS = 0.0f, dT = 0.0f;
    #pragma unroll
    for (int k = 0; k < 16; ++k) {
        float4 a = Si[k], b = Sj[k];
        dS += a.x * b.x + a.y * b.y + a.z * b.z + a.w * b.w;
        float4 c = Ti[k], d = Tj[k];
        dT += c.x * d.x + c.y * d.y + c.z * d.z + c.w * d.w;
    }
    __shared__ float sS[4][64], sT[4][64];
    sS[seg][j] = dS;
    sT[seg][j] = dT;
    __syncthreads();
    if (t < 64) {
        float fS = sS[0][t] + sS[1][t] + sS[2][t] + sS[3][t];
        float fT = sT[0][t] + sT[1][t] + sT[2][t] + sT[3][t];
        float e = fS - fT;
        e = e * e;
        #pragma unroll
        for (int o = 32; o; o >>= 1) e += __shfl_xor(e, o, 64);
        if (t == 0) {
            atomicAdd(acc, e);
            __threadfence();
            unsigned int r = atomicAdd(ticket, 1u);
            if (r == NB - 1) {
                float tot = atomicAdd(acc, 0.0f);   // device-scope read
                out[0] = tot * (1.0f / (float)(NB * NB));
            }
        }
    }
}

extern "C" void kernel_launch(void* const* d_in, const int* in_sizes, int n_in,
                              void* d_out, int out_size, void* d_ws, size_t ws_size,
                              hipStream_t stream) {
    const float* predsS = (const float*)d_in[0];
    const float* predsT = (const float*)d_in[1];
    const float* depth  = (const float*)d_in[2];
    char* ws = (char*)d_ws;
    float* sums = (float*)ws;
    int* counts = (int*)(ws + WS_COUNTS);
    float* acc = (float*)(ws + WS_ACC);
    unsigned int* ticket = (unsigned int*)(ws + WS_TICKET);
    float* pS = (float*)(ws + WS_PS);
    float* pT = (float*)(ws + WS_PT);

    hipMemsetAsync(ws, 0, WS_ZERO, stream);
    k_msum<<<GRID_MS, 256, 0, stream>>>(predsS, predsT, depth, sums, counts);
    k_protos<<<NB, 256, 0, stream>>>(sums, counts, pS, pT);
    k_sim<<<NB, 256, 0, stream>>>(pS, pT, acc, ticket, (float*)d_out);
}